// Round 1
// baseline (1039.195 us; speedup 1.0000x reference)
//
#include <hip/hip_runtime.h>

#define D 1024
#define NB1 48
#define NB2 48
#define RR 36
#define LL 30
#define NH 4

// ---------------- generic fp32 GEMM: C[m][n] = scale * sum_k A[m][k]*B[n][k], K = 1024 ----------------
__global__ __launch_bounds__(256) void gemm_abt(const float* __restrict__ A,
                                                const float* __restrict__ B,
                                                float* __restrict__ C,
                                                int M, int N, float scale) {
  __shared__ float As[16][68];   // padded: write banks ~2-way, float4-aligned rows
  __shared__ float Bs[16][68];
  const int bn = blockIdx.x * 64;
  const int bm = blockIdx.y * 64;
  const int t = threadIdx.x;
  const int tx = t & 15, ty = t >> 4;
  const int lm = t >> 2;          // 0..63 : row within tile
  const int lk = (t & 3) << 2;    // 0,4,8,12 : k within tile

  float acc[4][4];
#pragma unroll
  for (int i = 0; i < 4; ++i)
#pragma unroll
    for (int j = 0; j < 4; ++j) acc[i][j] = 0.f;

  for (int k0 = 0; k0 < D; k0 += 16) {
    float4 av = make_float4(0.f, 0.f, 0.f, 0.f);
    float4 bv = make_float4(0.f, 0.f, 0.f, 0.f);
    if (bm + lm < M) av = *(const float4*)&A[(size_t)(bm + lm) * D + k0 + lk];
    if (bn + lm < N) bv = *(const float4*)&B[(size_t)(bn + lm) * D + k0 + lk];
    As[lk + 0][lm] = av.x; As[lk + 1][lm] = av.y; As[lk + 2][lm] = av.z; As[lk + 3][lm] = av.w;
    Bs[lk + 0][lm] = bv.x; Bs[lk + 1][lm] = bv.y; Bs[lk + 2][lm] = bv.z; Bs[lk + 3][lm] = bv.w;
    __syncthreads();
#pragma unroll
    for (int kk = 0; kk < 16; ++kk) {
      float4 a4 = *(const float4*)&As[kk][ty << 2];
      float4 b4 = *(const float4*)&Bs[kk][tx << 2];
      float ar[4] = {a4.x, a4.y, a4.z, a4.w};
      float br[4] = {b4.x, b4.y, b4.z, b4.w};
#pragma unroll
      for (int i = 0; i < 4; ++i)
#pragma unroll
        for (int j = 0; j < 4; ++j) acc[i][j] = fmaf(ar[i], br[j], acc[i][j]);
    }
    __syncthreads();
  }
#pragma unroll
  for (int i = 0; i < 4; ++i) {
    int m = bm + (ty << 2) + i;
    if (m < M) {
      float4 o = make_float4(acc[i][0] * scale, acc[i][1] * scale,
                             acc[i][2] * scale, acc[i][3] * scale);
      *(float4*)&C[(size_t)m * N + bn + (tx << 2)] = o;
    }
  }
}

// ---------------- per-batch Gram matrices: out[blk][i][j] = v[blk,i,:] . v[blk,j,:] ----------------
__global__ __launch_bounds__(256) void gram_kernel(const float* __restrict__ V,
                                                   float* __restrict__ out, int Nrows) {
  const int blk = blockIdx.x;
  const float* base = V + (size_t)blk * Nrows * D;
  __shared__ float vs[36 * 65];   // padded stride 65 -> conflict-free stride-64 access
  const int t = threadIdx.x;
  const int NN = Nrows * Nrows;
  int io[6], jo[6];
#pragma unroll
  for (int oi = 0; oi < 6; ++oi) {
    int o = t + oi * 256;
    io[oi] = o / Nrows;
    jo[oi] = o - io[oi] * Nrows;
  }
  float acc[6] = {0.f, 0.f, 0.f, 0.f, 0.f, 0.f};
  for (int c = 0; c < 16; ++c) {
    for (int idx = t; idx < Nrows * 64; idx += 256) {
      int row = idx >> 6, kk = idx & 63;
      vs[row * 65 + kk] = base[(size_t)row * D + c * 64 + kk];
    }
    __syncthreads();
#pragma unroll
    for (int oi = 0; oi < 6; ++oi) {
      int o = t + oi * 256;
      if (o < NN) {
        const float* vi = &vs[io[oi] * 65];
        const float* vj = &vs[jo[oi] * 65];
        float x = acc[oi];
#pragma unroll 8
        for (int kk = 0; kk < 64; ++kk) x = fmaf(vi[kk], vj[kk], x);
        acc[oi] = x;
      }
    }
    __syncthreads();
  }
  for (int oi = 0; oi < 6; ++oi) {
    int o = t + oi * 256;
    if (o < NN) out[(size_t)blk * NN + o] = acc[oi];
  }
}

// ---------------- per-(a,b) pair kernel: softmaxes, MLP scores, final bilinear forms ----------------
__global__ __launch_bounds__(256) void pair_kernel(
    const float* __restrict__ Sb, const float* __restrict__ Cb,
    const float* __restrict__ G2a, const float* __restrict__ G1b,
    const float* __restrict__ g22, const float* __restrict__ g11,
    const float* __restrict__ b1a, const float* __restrict__ w2a, const float* __restrict__ b2a,
    const float* __restrict__ b1b, const float* __restrict__ w2b, const float* __restrict__ b2b,
    float* __restrict__ out) {
  const int pair = blockIdx.x;
  const int a = pair / NB2;
  const int b = pair - a * NB2;
  const int t = threadIdx.x;

  __shared__ float sm_s[LL][RR];
  __shared__ float sm_p1[LL][RR];    // softmax over r (rows), row stride 36 floats (16B-aligned)
  __shared__ float sm_p2[RR][32];    // softmax over l (cols of s), padded to 32 for float4
  __shared__ float hbuf[RR][260];    // relu(hidden) chunk, pad 260 (float4-aligned, conflict-free)
  __shared__ float w2s[NH][260];
  __shared__ float sa[RR][NH];
  __shared__ float sbm[LL][NH];
  __shared__ float qa[RR], qb[LL], u1[RR], u2[LL];
  __shared__ float redbuf[3][4];

  // 1. load scaled scores s1[a,b,l,r]
  for (int i = t; i < LL * RR; i += 256) {
    int l = i / RR, r = i - l * RR;
    sm_s[l][r] = Sb[(size_t)(b * LL + l) * 1728 + a * RR + r];
  }
  __syncthreads();

  // 2. p1 = softmax over r (per l row); p2 = softmax over l (per r column)
  if (t < LL) {
    float m = -1e30f;
    for (int r = 0; r < RR; ++r) m = fmaxf(m, sm_s[t][r]);
    float s = 0.f;
    for (int r = 0; r < RR; ++r) { float e = __expf(sm_s[t][r] - m); sm_p1[t][r] = e; s += e; }
    float inv = 1.f / s;
    for (int r = 0; r < RR; ++r) sm_p1[t][r] *= inv;
  } else if (t >= 64 && t < 64 + RR) {
    int r = t - 64;
    float m = -1e30f;
    for (int l = 0; l < LL; ++l) m = fmaxf(m, sm_s[l][r]);
    float s = 0.f;
    for (int l = 0; l < LL; ++l) { float e = __expf(sm_s[l][r] - m); sm_p2[r][l] = e; s += e; }
    float inv = 1.f / s;
    for (int l = 0; l < LL; ++l) sm_p2[r][l] *= inv;
  }
  __syncthreads();

  // 3a. score_a[r][h] = b2a + sum_e relu(b1a[e] + sum_l p2[r][l] G2a[b,l,e]) * w2a[h][e]
  float accA = 0.f;
  {
    const float* Gb = G2a + (size_t)b * LL * D;
    for (int c = 0; c < 4; ++c) {
      const int e = c * 256 + t;
#pragma unroll
      for (int h = 0; h < NH; ++h) w2s[h][t] = w2a[h * D + e];
      float g[LL];
#pragma unroll
      for (int l = 0; l < LL; ++l) g[l] = Gb[l * D + e];
      const float be = b1a[e];
      for (int r = 0; r < RR; ++r) {
        float hv = be;
        const float4* p4 = (const float4*)&sm_p2[r][0];
#pragma unroll
        for (int l4 = 0; l4 < 7; ++l4) {
          float4 pv = p4[l4];
          hv = fmaf(pv.x, g[4 * l4 + 0], hv);
          hv = fmaf(pv.y, g[4 * l4 + 1], hv);
          hv = fmaf(pv.z, g[4 * l4 + 2], hv);
          hv = fmaf(pv.w, g[4 * l4 + 3], hv);
        }
        hv = fmaf(sm_p2[r][28], g[28], hv);
        hv = fmaf(sm_p2[r][29], g[29], hv);
        hbuf[r][t] = fmaxf(hv, 0.f);
      }
      __syncthreads();
      if (t < RR * NH) {
        const int r = t >> 2, h = t & 3;
        const float4* hb = (const float4*)&hbuf[r][0];
        const float4* wb = (const float4*)&w2s[h][0];
        float x = 0.f;
#pragma unroll 8
        for (int q = 0; q < 64; ++q) {
          float4 hh = hb[q]; float4 ww = wb[q];
          x = fmaf(hh.x, ww.x, x); x = fmaf(hh.y, ww.y, x);
          x = fmaf(hh.z, ww.z, x); x = fmaf(hh.w, ww.w, x);
        }
        accA += x;
      }
      __syncthreads();
    }
    if (t < RR * NH) sa[t >> 2][t & 3] = accA + b2a[t & 3];
  }

  // 3b. score_b[l][h] = b2b + sum_e relu(b1b[e] + sum_r p1[l][r] G1b[a,r,e]) * w2b[h][e]
  float accB = 0.f;
  {
    const float* Ga = G1b + (size_t)a * RR * D;
    for (int c = 0; c < 4; ++c) {
      const int e = c * 256 + t;
#pragma unroll
      for (int h = 0; h < NH; ++h) w2s[h][t] = w2b[h * D + e];
      float g[RR];
#pragma unroll
      for (int r = 0; r < RR; ++r) g[r] = Ga[r * D + e];
      const float be = b1b[e];
      for (int l = 0; l < LL; ++l) {
        float hv = be;
        const float4* p4 = (const float4*)&sm_p1[l][0];
#pragma unroll
        for (int r4 = 0; r4 < 9; ++r4) {
          float4 pv = p4[r4];
          hv = fmaf(pv.x, g[4 * r4 + 0], hv);
          hv = fmaf(pv.y, g[4 * r4 + 1], hv);
          hv = fmaf(pv.z, g[4 * r4 + 2], hv);
          hv = fmaf(pv.w, g[4 * r4 + 3], hv);
        }
        hbuf[l][t] = fmaxf(hv, 0.f);
      }
      __syncthreads();
      if (t < LL * NH) {
        const int l = t >> 2, h = t & 3;
        const float4* hb = (const float4*)&hbuf[l][0];
        const float4* wb = (const float4*)&w2s[h][0];
        float x = 0.f;
#pragma unroll 8
        for (int q = 0; q < 64; ++q) {
          float4 hh = hb[q]; float4 ww = wb[q];
          x = fmaf(hh.x, ww.x, x); x = fmaf(hh.y, ww.y, x);
          x = fmaf(hh.z, ww.z, x); x = fmaf(hh.w, ww.w, x);
        }
        accB += x;
      }
      __syncthreads();
    }
    if (t < LL * NH) sbm[t >> 2][t & 3] = accB + b2b[t & 3];
  }
  __syncthreads();

  // 4. per-head softmax over n, q = mean over heads
  if (t < NH) {
    const int h = t;
    float m = -1e30f;
    for (int r = 0; r < RR; ++r) m = fmaxf(m, sa[r][h]);
    float s = 0.f;
    for (int r = 0; r < RR; ++r) { float e = __expf(sa[r][h] - m); sa[r][h] = e; s += e; }
    float inv = 1.f / s;
    for (int r = 0; r < RR; ++r) sa[r][h] *= inv;
  } else if (t >= 64 && t < 64 + NH) {
    const int h = t - 64;
    float m = -1e30f;
    for (int l = 0; l < LL; ++l) m = fmaxf(m, sbm[l][h]);
    float s = 0.f;
    for (int l = 0; l < LL; ++l) { float e = __expf(sbm[l][h] - m); sbm[l][h] = e; s += e; }
    float inv = 1.f / s;
    for (int l = 0; l < LL; ++l) sbm[l][h] *= inv;
  }
  __syncthreads();
  if (t < RR) qa[t] = 0.25f * (sa[t][0] + sa[t][1] + sa[t][2] + sa[t][3]);
  else if (t >= 64 && t < 64 + LL) {
    int l = t - 64;
    qb[l] = 0.25f * (sbm[l][0] + sbm[l][1] + sbm[l][2] + sbm[l][3]);
  }
  __syncthreads();

  // 5. u2[l] = sum_r qa[r] p2[r][l] ; u1[r] = sum_l qb[l] p1[l][r]
  if (t < LL) {
    float x = 0.f;
    for (int r = 0; r < RR; ++r) x = fmaf(qa[r], sm_p2[r][t], x);
    u2[t] = x;
  } else if (t >= 64 && t < 64 + RR) {
    int r = t - 64;
    float x = 0.f;
    for (int l = 0; l < LL; ++l) x = fmaf(qb[l], sm_p1[l][r], x);
    u1[r] = x;
  }
  __syncthreads();

  // 6. num = u2' C u1 ; |co_v1|^2 = u2' G22 u2 ; |co_v2|^2 = u1' G11 u1
  float pnum = 0.f, pn1 = 0.f, pn2 = 0.f;
  {
    const float* Cab = Cb + (size_t)(b * LL) * 1728 + a * RR;
    for (int i = t; i < LL * RR; i += 256) {
      int l = i / RR, r = i - l * RR;
      pnum = fmaf(u2[l] * u1[r], Cab[(size_t)l * 1728 + r], pnum);
    }
    const float* G22 = g22 + (size_t)b * LL * LL;
    for (int i = t; i < LL * LL; i += 256) {
      int l = i / LL, l2 = i - l * LL;
      pn1 = fmaf(u2[l] * u2[l2], G22[i], pn1);
    }
    const float* G11 = g11 + (size_t)a * RR * RR;
    for (int i = t; i < RR * RR; i += 256) {
      int r = i / RR, r2 = i - r * RR;
      pn2 = fmaf(u1[r] * u1[r2], G11[i], pn2);
    }
  }
#pragma unroll
  for (int off = 32; off > 0; off >>= 1) {
    pnum += __shfl_down(pnum, off);
    pn1  += __shfl_down(pn1, off);
    pn2  += __shfl_down(pn2, off);
  }
  const int wave = t >> 6, lane = t & 63;
  if (lane == 0) { redbuf[0][wave] = pnum; redbuf[1][wave] = pn1; redbuf[2][wave] = pn2; }
  __syncthreads();
  if (t == 0) {
    float num = redbuf[0][0] + redbuf[0][1] + redbuf[0][2] + redbuf[0][3];
    float n1s = redbuf[1][0] + redbuf[1][1] + redbuf[1][2] + redbuf[1][3];
    float n2s = redbuf[2][0] + redbuf[2][1] + redbuf[2][2] + redbuf[2][3];
    float n1 = sqrtf(fmaxf(n1s, 0.f));
    float n2 = sqrtf(fmaxf(n2s, 0.f));
    out[pair] = num / ((n1 + 1e-8f) * (n2 + 1e-8f));
  }
}

extern "C" void kernel_launch(void* const* d_in, const int* in_sizes, int n_in,
                              void* d_out, int out_size, void* d_ws, size_t ws_size,
                              hipStream_t stream) {
  const float* v1    = (const float*)d_in[0];
  const float* v2    = (const float*)d_in[1];
  const float* w_img = (const float*)d_in[2];
  const float* w_txt = (const float*)d_in[3];
  const float* w1a   = (const float*)d_in[4];
  const float* b1a   = (const float*)d_in[5];
  const float* w2a   = (const float*)d_in[6];
  const float* b2a   = (const float*)d_in[7];
  const float* w1b   = (const float*)d_in[8];
  const float* b1b   = (const float*)d_in[9];
  const float* w2b   = (const float*)d_in[10];
  const float* b2b   = (const float*)d_in[11];
  float* out = (float*)d_out;

  // workspace layout (fp32), total ~44.1 MiB
  float* ws   = (float*)d_ws;
  float* k1   = ws;                                   // 1728*1024
  float* k2   = k1 + (size_t)1728 * 1024;             // 1440*1024
  float* G2a  = k2 + (size_t)1440 * 1024;             // 1440*1024
  float* G1b  = G2a + (size_t)1440 * 1024;            // 1728*1024
  float* Sbuf = G1b + (size_t)1728 * 1024;            // 1440*1728 : [b*30+l][a*36+r]
  float* Cbuf = Sbuf + (size_t)1440 * 1728;           // 1440*1728
  float* g22  = Cbuf + (size_t)1440 * 1728;           // 48*30*30
  float* g11  = g22 + (size_t)48 * 900;               // 48*36*36

  // k1 = v1 @ w_img^T ; k2 = v2 @ w_txt^T ; G2a = v2 @ w1a^T ; G1b = v1 @ w1b^T
  gemm_abt<<<dim3(16, 27), 256, 0, stream>>>(v1, w_img, k1, 1728, 1024, 1.f);
  gemm_abt<<<dim3(16, 23), 256, 0, stream>>>(v2, w_txt, k2, 1440, 1024, 1.f);
  gemm_abt<<<dim3(16, 23), 256, 0, stream>>>(v2, w1a, G2a, 1440, 1024, 1.f);
  gemm_abt<<<dim3(16, 27), 256, 0, stream>>>(v1, w1b, G1b, 1728, 1024, 1.f);
  // S[(b,l),(a,r)] = k2 . k1 / 32 ; C[(b,l),(a,r)] = v2 . v1
  gemm_abt<<<dim3(27, 23), 256, 0, stream>>>(k2, k1, Sbuf, 1440, 1728, 0.03125f);
  gemm_abt<<<dim3(27, 23), 256, 0, stream>>>(v2, v1, Cbuf, 1440, 1728, 1.f);
  // Gram matrices
  gram_kernel<<<48, 256, 0, stream>>>(v1, g11, 36);
  gram_kernel<<<48, 256, 0, stream>>>(v2, g22, 30);
  // per-pair fusion
  pair_kernel<<<2304, 256, 0, stream>>>(Sbuf, Cbuf, G2a, G1b, g22, g11,
                                        b1a, w2a, b2a, b1b, w2b, b2b, out);
}

// Round 2
// 735.799 us; speedup vs baseline: 1.4123x; 1.4123x over previous
//
#include <hip/hip_runtime.h>

#define D 1024
#define NB1 48
#define NB2 48
#define RR 36
#define LL 30
#define NH 4

typedef short bf16x8 __attribute__((ext_vector_type(8)));
typedef float f32x4 __attribute__((ext_vector_type(4)));
typedef unsigned short u16x8 __attribute__((ext_vector_type(8)));

#define MFMA16(a, b, c) __builtin_amdgcn_mfma_f32_16x16x32_bf16(a, b, c, 0, 0, 0)

__device__ __forceinline__ unsigned short f2bf(float x) {
  unsigned u = __float_as_uint(x);
  u += 0x7FFF + ((u >> 16) & 1);   // RN-even; inputs finite
  return (unsigned short)(u >> 16);
}
__device__ __forceinline__ float bf2f(unsigned short h) {
  return __uint_as_float(((unsigned)h) << 16);
}

// ---- fp32 row-major (rows x 1024) -> split-bf16 MFMA fragment layout ----
// chunk g = tile*32+kc holds: part0(hi) 512 ush, part1(lo) 512 ush.
// lane's 8 elems = X[tile*16+(lane&15)][kc*32+(lane>>4)*8 + j]. rows>=param zero-filled.
__global__ __launch_bounds__(256) void convert_frag(const float* __restrict__ X,
                                                    unsigned short* __restrict__ out,
                                                    int rows) {
  const int lane = threadIdx.x & 63;
  const int g = blockIdx.x * 4 + (threadIdx.x >> 6);
  const int tile = g >> 5, kc = g & 31;
  const int row = tile * 16 + (lane & 15);
  const int k = kc * 32 + (lane >> 4) * 8;
  float v[8];
  if (row < rows) {
    const float4* s = (const float4*)(X + (size_t)row * 1024 + k);
    float4 x0 = s[0], x1 = s[1];
    v[0] = x0.x; v[1] = x0.y; v[2] = x0.z; v[3] = x0.w;
    v[4] = x1.x; v[5] = x1.y; v[6] = x1.z; v[7] = x1.w;
  } else {
#pragma unroll
    for (int i = 0; i < 8; ++i) v[i] = 0.f;
  }
  u16x8 hi, lo;
#pragma unroll
  for (int i = 0; i < 8; ++i) {
    unsigned short h = f2bf(v[i]);
    hi[i] = h;
    lo[i] = f2bf(v[i] - bf2f(h));
  }
  u16x8* o = (u16x8*)(out + (size_t)g * 1024 + lane * 8);
  o[0]  = hi;   // part 0
  o[64] = lo;   // part 1 (+512 ushorts)
}

// ---- split-bf16 MFMA GEMM: C[m][n] = scale * sum_k A[m][k]*B[n][k], K=1024 ----
// Af/Bf in fragment layout (16-row tiles). No LDS, no barriers: direct frag loads.
__global__ __launch_bounds__(256) void mfma_gemm_abt(const bf16x8* __restrict__ Af,
                                                     const bf16x8* __restrict__ Bf,
                                                     float* __restrict__ C,
                                                     int M, int N, float scale) {
  const int lane = threadIdx.x & 63;
  const int w = threadIdx.x >> 6;
  const int mt0 = blockIdx.y * 4 + (w >> 1) * 2;  // 16-row tile index
  const int nt0 = blockIdx.x * 4 + (w & 1) * 2;
  f32x4 acc00 = {0.f, 0.f, 0.f, 0.f}, acc01 = {0.f, 0.f, 0.f, 0.f};
  f32x4 acc10 = {0.f, 0.f, 0.f, 0.f}, acc11 = {0.f, 0.f, 0.f, 0.f};
  size_t a0 = (size_t)mt0 * 4096 + lane;  // per-tile stride = 32 kc * 2 part * 64 lane
  size_t a1 = a0 + 4096;
  size_t b0 = (size_t)nt0 * 4096 + lane;
  size_t b1 = b0 + 4096;
#pragma unroll 2
  for (int kc = 0; kc < 32; ++kc) {
    bf16x8 a0h = Af[a0], a0l = Af[a0 + 64];
    bf16x8 a1h = Af[a1], a1l = Af[a1 + 64];
    bf16x8 b0h = Bf[b0], b0l = Bf[b0 + 64];
    bf16x8 b1h = Bf[b1], b1l = Bf[b1 + 64];
    a0 += 128; a1 += 128; b0 += 128; b1 += 128;
    acc00 = MFMA16(a0h, b0h, acc00);
    acc00 = MFMA16(a0l, b0h, acc00);
    acc00 = MFMA16(a0h, b0l, acc00);
    acc01 = MFMA16(a0h, b1h, acc01);
    acc01 = MFMA16(a0l, b1h, acc01);
    acc01 = MFMA16(a0h, b1l, acc01);
    acc10 = MFMA16(a1h, b0h, acc10);
    acc10 = MFMA16(a1l, b0h, acc10);
    acc10 = MFMA16(a1h, b0l, acc10);
    acc11 = MFMA16(a1h, b1h, acc11);
    acc11 = MFMA16(a1l, b1h, acc11);
    acc11 = MFMA16(a1h, b1l, acc11);
  }
  const int col = nt0 * 16 + (lane & 15);
  const int r0 = mt0 * 16 + ((lane >> 4) << 2);
#pragma unroll
  for (int reg = 0; reg < 4; ++reg) {
    int r = r0 + reg;
    if (r < M) {
      C[(size_t)r * N + col] = acc00[reg] * scale;
      C[(size_t)r * N + col + 16] = acc01[reg] * scale;
    }
    if (r + 16 < M) {
      C[(size_t)(r + 16) * N + col] = acc10[reg] * scale;
      C[(size_t)(r + 16) * N + col + 16] = acc11[reg] * scale;
    }
  }
}

// ---------------- per-batch Gram matrices: out[blk][i][j] = v[blk,i,:] . v[blk,j,:] ----------------
__global__ __launch_bounds__(256) void gram_kernel(const float* __restrict__ V,
                                                   float* __restrict__ out, int Nrows) {
  const int blk = blockIdx.x;
  const float* base = V + (size_t)blk * Nrows * D;
  __shared__ float vs[36 * 65];
  const int t = threadIdx.x;
  const int NN = Nrows * Nrows;
  int io[6], jo[6];
#pragma unroll
  for (int oi = 0; oi < 6; ++oi) {
    int o = t + oi * 256;
    io[oi] = o / Nrows;
    jo[oi] = o - io[oi] * Nrows;
  }
  float acc[6] = {0.f, 0.f, 0.f, 0.f, 0.f, 0.f};
  for (int c = 0; c < 16; ++c) {
    for (int idx = t; idx < Nrows * 64; idx += 256) {
      int row = idx >> 6, kk = idx & 63;
      vs[row * 65 + kk] = base[(size_t)row * D + c * 64 + kk];
    }
    __syncthreads();
#pragma unroll
    for (int oi = 0; oi < 6; ++oi) {
      int o = t + oi * 256;
      if (o < NN) {
        const float* vi = &vs[io[oi] * 65];
        const float* vj = &vs[jo[oi] * 65];
        float x = acc[oi];
#pragma unroll 8
        for (int kk = 0; kk < 64; ++kk) x = fmaf(vi[kk], vj[kk], x);
        acc[oi] = x;
      }
    }
    __syncthreads();
  }
  for (int oi = 0; oi < 6; ++oi) {
    int o = t + oi * 256;
    if (o < NN) out[(size_t)blk * NN + o] = acc[oi];
  }
}

// ---------------- per-(a,b) pair kernel: softmaxes, MLP scores, final bilinear forms ----------------
__global__ __launch_bounds__(256) void pair_kernel(
    const float* __restrict__ Sb, const float* __restrict__ Cb,
    const float* __restrict__ G2a, const float* __restrict__ G1b,
    const float* __restrict__ g22, const float* __restrict__ g11,
    const float* __restrict__ b1a, const float* __restrict__ w2a, const float* __restrict__ b2a,
    const float* __restrict__ b1b, const float* __restrict__ w2b, const float* __restrict__ b2b,
    float* __restrict__ out) {
  const int pair = blockIdx.x;
  const int a = pair / NB2;
  const int b = pair - a * NB2;
  const int t = threadIdx.x;

  __shared__ float sm_s[LL][RR];
  __shared__ float sm_p1[LL][RR];
  __shared__ float sm_p2[RR][32];
  __shared__ float hbuf[RR][260];
  __shared__ float w2s[NH][260];
  __shared__ float sa[RR][NH];
  __shared__ float sbm[LL][NH];
  __shared__ float qa[RR], qb[LL], u1[RR], u2[LL];
  __shared__ float redbuf[3][4];

  for (int i = t; i < LL * RR; i += 256) {
    int l = i / RR, r = i - l * RR;
    sm_s[l][r] = Sb[(size_t)(b * LL + l) * 1728 + a * RR + r];
  }
  __syncthreads();

  if (t < LL) {
    float m = -1e30f;
    for (int r = 0; r < RR; ++r) m = fmaxf(m, sm_s[t][r]);
    float s = 0.f;
    for (int r = 0; r < RR; ++r) { float e = __expf(sm_s[t][r] - m); sm_p1[t][r] = e; s += e; }
    float inv = 1.f / s;
    for (int r = 0; r < RR; ++r) sm_p1[t][r] *= inv;
  } else if (t >= 64 && t < 64 + RR) {
    int r = t - 64;
    float m = -1e30f;
    for (int l = 0; l < LL; ++l) m = fmaxf(m, sm_s[l][r]);
    float s = 0.f;
    for (int l = 0; l < LL; ++l) { float e = __expf(sm_s[l][r] - m); sm_p2[r][l] = e; s += e; }
    float inv = 1.f / s;
    for (int l = 0; l < LL; ++l) sm_p2[r][l] *= inv;
  }
  __syncthreads();

  float accA = 0.f;
  {
    const float* Gb = G2a + (size_t)b * LL * D;
    for (int c = 0; c < 4; ++c) {
      const int e = c * 256 + t;
#pragma unroll
      for (int h = 0; h < NH; ++h) w2s[h][t] = w2a[h * D + e];
      float g[LL];
#pragma unroll
      for (int l = 0; l < LL; ++l) g[l] = Gb[l * D + e];
      const float be = b1a[e];
      for (int r = 0; r < RR; ++r) {
        float hv = be;
        const float4* p4 = (const float4*)&sm_p2[r][0];
#pragma unroll
        for (int l4 = 0; l4 < 7; ++l4) {
          float4 pv = p4[l4];
          hv = fmaf(pv.x, g[4 * l4 + 0], hv);
          hv = fmaf(pv.y, g[4 * l4 + 1], hv);
          hv = fmaf(pv.z, g[4 * l4 + 2], hv);
          hv = fmaf(pv.w, g[4 * l4 + 3], hv);
        }
        hv = fmaf(sm_p2[r][28], g[28], hv);
        hv = fmaf(sm_p2[r][29], g[29], hv);
        hbuf[r][t] = fmaxf(hv, 0.f);
      }
      __syncthreads();
      if (t < RR * NH) {
        const int r = t >> 2, h = t & 3;
        const float4* hb = (const float4*)&hbuf[r][0];
        const float4* wb = (const float4*)&w2s[h][0];
        float x = 0.f;
#pragma unroll 8
        for (int q = 0; q < 64; ++q) {
          float4 hh = hb[q]; float4 ww = wb[q];
          x = fmaf(hh.x, ww.x, x); x = fmaf(hh.y, ww.y, x);
          x = fmaf(hh.z, ww.z, x); x = fmaf(hh.w, ww.w, x);
        }
        accA += x;
      }
      __syncthreads();
    }
    if (t < RR * NH) sa[t >> 2][t & 3] = accA + b2a[t & 3];
  }

  float accB = 0.f;
  {
    const float* Ga = G1b + (size_t)a * RR * D;
    for (int c = 0; c < 4; ++c) {
      const int e = c * 256 + t;
#pragma unroll
      for (int h = 0; h < NH; ++h) w2s[h][t] = w2b[h * D + e];
      float g[RR];
#pragma unroll
      for (int r = 0; r < RR; ++r) g[r] = Ga[r * D + e];
      const float be = b1b[e];
      for (int l = 0; l < LL; ++l) {
        float hv = be;
        const float4* p4 = (const float4*)&sm_p1[l][0];
#pragma unroll
        for (int r4 = 0; r4 < 9; ++r4) {
          float4 pv = p4[r4];
          hv = fmaf(pv.x, g[4 * r4 + 0], hv);
          hv = fmaf(pv.y, g[4 * r4 + 1], hv);
          hv = fmaf(pv.z, g[4 * r4 + 2], hv);
          hv = fmaf(pv.w, g[4 * r4 + 3], hv);
        }
        hbuf[l][t] = fmaxf(hv, 0.f);
      }
      __syncthreads();
      if (t < LL * NH) {
        const int l = t >> 2, h = t & 3;
        const float4* hb = (const float4*)&hbuf[l][0];
        const float4* wb = (const float4*)&w2s[h][0];
        float x = 0.f;
#pragma unroll 8
        for (int q = 0; q < 64; ++q) {
          float4 hh = hb[q]; float4 ww = wb[q];
          x = fmaf(hh.x, ww.x, x); x = fmaf(hh.y, ww.y, x);
          x = fmaf(hh.z, ww.z, x); x = fmaf(hh.w, ww.w, x);
        }
        accB += x;
      }
      __syncthreads();
    }
    if (t < LL * NH) sbm[t >> 2][t & 3] = accB + b2b[t & 3];
  }
  __syncthreads();

  if (t < NH) {
    const int h = t;
    float m = -1e30f;
    for (int r = 0; r < RR; ++r) m = fmaxf(m, sa[r][h]);
    float s = 0.f;
    for (int r = 0; r < RR; ++r) { float e = __expf(sa[r][h] - m); sa[r][h] = e; s += e; }
    float inv = 1.f / s;
    for (int r = 0; r < RR; ++r) sa[r][h] *= inv;
  } else if (t >= 64 && t < 64 + NH) {
    const int h = t - 64;
    float m = -1e30f;
    for (int l = 0; l < LL; ++l) m = fmaxf(m, sbm[l][h]);
    float s = 0.f;
    for (int l = 0; l < LL; ++l) { float e = __expf(sbm[l][h] - m); sbm[l][h] = e; s += e; }
    float inv = 1.f / s;
    for (int l = 0; l < LL; ++l) sbm[l][h] *= inv;
  }
  __syncthreads();
  if (t < RR) qa[t] = 0.25f * (sa[t][0] + sa[t][1] + sa[t][2] + sa[t][3]);
  else if (t >= 64 && t < 64 + LL) {
    int l = t - 64;
    qb[l] = 0.25f * (sbm[l][0] + sbm[l][1] + sbm[l][2] + sbm[l][3]);
  }
  __syncthreads();

  if (t < LL) {
    float x = 0.f;
    for (int r = 0; r < RR; ++r) x = fmaf(qa[r], sm_p2[r][t], x);
    u2[t] = x;
  } else if (t >= 64 && t < 64 + RR) {
    int r = t - 64;
    float x = 0.f;
    for (int l = 0; l < LL; ++l) x = fmaf(qb[l], sm_p1[l][r], x);
    u1[r] = x;
  }
  __syncthreads();

  float pnum = 0.f, pn1 = 0.f, pn2 = 0.f;
  {
    const float* Cab = Cb + (size_t)(b * LL) * 1728 + a * RR;
    for (int i = t; i < LL * RR; i += 256) {
      int l = i / RR, r = i - l * RR;
      pnum = fmaf(u2[l] * u1[r], Cab[(size_t)l * 1728 + r], pnum);
    }
    const float* G22 = g22 + (size_t)b * LL * LL;
    for (int i = t; i < LL * LL; i += 256) {
      int l = i / LL, l2 = i - l * LL;
      pn1 = fmaf(u2[l] * u2[l2], G22[i], pn1);
    }
    const float* G11 = g11 + (size_t)a * RR * RR;
    for (int i = t; i < RR * RR; i += 256) {
      int r = i / RR, r2 = i - r * RR;
      pn2 = fmaf(u1[r] * u1[r2], G11[i], pn2);
    }
  }
#pragma unroll
  for (int off = 32; off > 0; off >>= 1) {
    pnum += __shfl_down(pnum, off);
    pn1  += __shfl_down(pn1, off);
    pn2  += __shfl_down(pn2, off);
  }
  const int wave = t >> 6, lane = t & 63;
  if (lane == 0) { redbuf[0][wave] = pnum; redbuf[1][wave] = pn1; redbuf[2][wave] = pn2; }
  __syncthreads();
  if (t == 0) {
    float num = redbuf[0][0] + redbuf[0][1] + redbuf[0][2] + redbuf[0][3];
    float n1s = redbuf[1][0] + redbuf[1][1] + redbuf[1][2] + redbuf[1][3];
    float n2s = redbuf[2][0] + redbuf[2][1] + redbuf[2][2] + redbuf[2][3];
    float n1 = sqrtf(fmaxf(n1s, 0.f));
    float n2 = sqrtf(fmaxf(n2s, 0.f));
    out[pair] = num / ((n1 + 1e-8f) * (n2 + 1e-8f));
  }
}

extern "C" void kernel_launch(void* const* d_in, const int* in_sizes, int n_in,
                              void* d_out, int out_size, void* d_ws, size_t ws_size,
                              hipStream_t stream) {
  const float* v1    = (const float*)d_in[0];
  const float* v2    = (const float*)d_in[1];
  const float* w_img = (const float*)d_in[2];
  const float* w_txt = (const float*)d_in[3];
  const float* w1a   = (const float*)d_in[4];
  const float* b1a   = (const float*)d_in[5];
  const float* w2a   = (const float*)d_in[6];
  const float* b2a   = (const float*)d_in[7];
  const float* w1b   = (const float*)d_in[8];
  const float* b1b   = (const float*)d_in[9];
  const float* w2b   = (const float*)d_in[10];
  const float* b2b   = (const float*)d_in[11];
  float* out = (float*)d_out;

  // fp32 region (~46.3 MB)
  float* ws   = (float*)d_ws;
  float* k1   = ws;                           // 1728*1024
  float* k2   = k1 + (size_t)1728 * 1024;     // 1440*1024
  float* G2a  = k2 + (size_t)1440 * 1024;     // 1440*1024
  float* G1b  = G2a + (size_t)1440 * 1024;    // 1728*1024
  float* Sbuf = G1b + (size_t)1728 * 1024;    // 1440*1728
  float* Cbuf = Sbuf + (size_t)1440 * 1728;   // 1440*1728
  float* g22  = Cbuf + (size_t)1440 * 1728;   // 48*900
  float* g11  = g22 + (size_t)48 * 900;       // 48*1296

  // split-bf16 fragment region (~43 MB). tile = 16 rows; per tile 32768 ushorts.
  unsigned short* fb    = (unsigned short*)(g11 + (size_t)48 * 1296);
  unsigned short* v1f   = fb;                                  // 108 tiles
  unsigned short* v2f   = v1f + (size_t)108 * 32768;           //  92 tiles (1440 pad->1472)
  unsigned short* k1f   = v2f + (size_t)92 * 32768;            // 108 tiles
  unsigned short* k2f   = k1f + (size_t)108 * 32768;           //  92 tiles
  unsigned short* wimgf = k2f + (size_t)92 * 32768;            //  64 tiles
  unsigned short* wtxtf = wimgf + (size_t)64 * 32768;
  unsigned short* w1af  = wtxtf + (size_t)64 * 32768;
  unsigned short* w1bf  = w1af + (size_t)64 * 32768;

  // 1. split inputs into fragment layout
  convert_frag<<<108 * 8, 256, 0, stream>>>(v1, v1f, 1728);
  convert_frag<<< 92 * 8, 256, 0, stream>>>(v2, v2f, 1440);
  convert_frag<<< 64 * 8, 256, 0, stream>>>(w_img, wimgf, 1024);
  convert_frag<<< 64 * 8, 256, 0, stream>>>(w_txt, wtxtf, 1024);
  convert_frag<<< 64 * 8, 256, 0, stream>>>(w1a, w1af, 1024);
  convert_frag<<< 64 * 8, 256, 0, stream>>>(w1b, w1bf, 1024);

  // 2. projection GEMMs (MFMA split-bf16)
  mfma_gemm_abt<<<dim3(16, 27), 256, 0, stream>>>((const bf16x8*)v1f, (const bf16x8*)wimgf, k1, 1728, 1024, 1.f);
  mfma_gemm_abt<<<dim3(16, 23), 256, 0, stream>>>((const bf16x8*)v2f, (const bf16x8*)wtxtf, k2, 1440, 1024, 1.f);
  mfma_gemm_abt<<<dim3(16, 23), 256, 0, stream>>>((const bf16x8*)v2f, (const bf16x8*)w1af, G2a, 1440, 1024, 1.f);
  mfma_gemm_abt<<<dim3(16, 27), 256, 0, stream>>>((const bf16x8*)v1f, (const bf16x8*)w1bf, G1b, 1728, 1024, 1.f);

  // 3. split k1,k2
  convert_frag<<<108 * 8, 256, 0, stream>>>(k1, k1f, 1728);
  convert_frag<<< 92 * 8, 256, 0, stream>>>(k2, k2f, 1440);

  // 4. big cross GEMMs: S = k2.k1^T/32 ; C = v2.v1^T  (both 1440x1728)
  mfma_gemm_abt<<<dim3(27, 23), 256, 0, stream>>>((const bf16x8*)k2f, (const bf16x8*)k1f, Sbuf, 1440, 1728, 0.03125f);
  mfma_gemm_abt<<<dim3(27, 23), 256, 0, stream>>>((const bf16x8*)v2f, (const bf16x8*)v1f, Cbuf, 1440, 1728, 1.f);

  // 5. Gram matrices
  gram_kernel<<<48, 256, 0, stream>>>(v1, g11, 36);
  gram_kernel<<<48, 256, 0, stream>>>(v2, g22, 30);

  // 6. per-pair fusion
  pair_kernel<<<2304, 256, 0, stream>>>(Sbuf, Cbuf, G2a, G1b, g22, g11,
                                        b1a, w2a, b2a, b1b, w2b, b2b, out);
}

// Round 3
// 545.035 us; speedup vs baseline: 1.9067x; 1.3500x over previous
//
#include <hip/hip_runtime.h>

#define D 1024
#define NB1 48
#define NB2 48
#define RR 36
#define LL 30
#define NH 4

typedef short bf16x8 __attribute__((ext_vector_type(8)));
typedef float f32x4 __attribute__((ext_vector_type(4)));
typedef unsigned short u16x8 __attribute__((ext_vector_type(8)));

#define MFMA16(a, b, c) __builtin_amdgcn_mfma_f32_16x16x32_bf16(a, b, c, 0, 0, 0)

__device__ __forceinline__ unsigned short f2bf(float x) {
  unsigned u = __float_as_uint(x);
  u += 0x7FFF + ((u >> 16) & 1);
  return (unsigned short)(u >> 16);
}
__device__ __forceinline__ float bf2f(unsigned short h) {
  return __uint_as_float(((unsigned)h) << 16);
}
__device__ __forceinline__ void split8(const float* v, bf16x8& h8, bf16x8& l8) {
  u16x8 hi, lo;
#pragma unroll
  for (int i = 0; i < 8; ++i) {
    unsigned short h = f2bf(v[i]);
    hi[i] = h;
    lo[i] = f2bf(v[i] - bf2f(h));
  }
  h8 = __builtin_bit_cast(bf16x8, hi);
  l8 = __builtin_bit_cast(bf16x8, lo);
}

// ---- fp32 row-major (rows x 1024) -> split-bf16 MFMA fragment layout ----
__global__ __launch_bounds__(256) void convert_frag(const float* __restrict__ X,
                                                    unsigned short* __restrict__ out,
                                                    int rows) {
  const int lane = threadIdx.x & 63;
  const int g = blockIdx.x * 4 + (threadIdx.x >> 6);
  const int tile = g >> 5, kc = g & 31;
  const int row = tile * 16 + (lane & 15);
  const int k = kc * 32 + (lane >> 4) * 8;
  float v[8];
  if (row < rows) {
    const float4* s = (const float4*)(X + (size_t)row * 1024 + k);
    float4 x0 = s[0], x1 = s[1];
    v[0] = x0.x; v[1] = x0.y; v[2] = x0.z; v[3] = x0.w;
    v[4] = x1.x; v[5] = x1.y; v[6] = x1.z; v[7] = x1.w;
  } else {
#pragma unroll
    for (int i = 0; i < 8; ++i) v[i] = 0.f;
  }
  bf16x8 hi, lo;
  split8(v, hi, lo);
  bf16x8* o = (bf16x8*)(out + (size_t)g * 1024 + lane * 8);
  o[0] = hi;
  o[64] = lo;
}

// ---- G2a (fp32, rows b*30+l, cols e) -> B-frag [b][nt(64)][part(2)][512] ----
__global__ __launch_bounds__(256) void conv_g2a(const float* __restrict__ G,
                                                unsigned short* __restrict__ out) {
  const int t = threadIdx.x, lane = t & 63;
  const int b = blockIdx.x >> 4;
  const int nt = ((blockIdx.x & 15) << 2) + (t >> 6);
  const int c = lane & 15, q = lane >> 4;
  float v[8];
#pragma unroll
  for (int j = 0; j < 8; ++j) {
    int l = q * 8 + j;
    v[j] = (l < LL) ? G[(size_t)(b * LL + l) * D + nt * 16 + c] : 0.f;
  }
  bf16x8 hi, lo;
  split8(v, hi, lo);
  bf16x8* o = (bf16x8*)(out + ((size_t)(b * 64 + nt) * 2) * 512 + lane * 8);
  o[0] = hi;
  o[64] = lo;
}

// ---- G1b (fp32, rows a*36+r, cols e) -> B-frag [a][nt(64)][kc(2)][part(2)][512] ----
__global__ __launch_bounds__(256) void conv_g1b(const float* __restrict__ G,
                                                unsigned short* __restrict__ out) {
  const int t = threadIdx.x, lane = t & 63;
  const int a = blockIdx.x >> 4;
  const int nt = ((blockIdx.x & 15) << 2) + (t >> 6);
  const int c = lane & 15, q = lane >> 4;
#pragma unroll
  for (int kc = 0; kc < 2; ++kc) {
    float v[8];
#pragma unroll
    for (int j = 0; j < 8; ++j) {
      int r = kc * 32 + q * 8 + j;
      v[j] = (r < RR) ? G[(size_t)(a * RR + r) * D + nt * 16 + c] : 0.f;
    }
    bf16x8 hi, lo;
    split8(v, hi, lo);
    bf16x8* o = (bf16x8*)(out + (((size_t)(a * 64 + nt) * 2 + kc) * 2) * 512 + lane * 8);
    o[0] = hi;
    o[64] = lo;
  }
}

// ---- split-bf16 MFMA GEMM: C[m][n] = scale * sum_k A[m][k]*B[n][k], K=1024 ----
__global__ __launch_bounds__(256) void mfma_gemm_abt(const bf16x8* __restrict__ Af,
                                                     const bf16x8* __restrict__ Bf,
                                                     float* __restrict__ C,
                                                     int M, int N, float scale) {
  const int lane = threadIdx.x & 63;
  const int w = threadIdx.x >> 6;
  const int mt0 = blockIdx.y * 4 + (w >> 1) * 2;
  const int nt0 = blockIdx.x * 4 + (w & 1) * 2;
  f32x4 acc00 = {0.f, 0.f, 0.f, 0.f}, acc01 = {0.f, 0.f, 0.f, 0.f};
  f32x4 acc10 = {0.f, 0.f, 0.f, 0.f}, acc11 = {0.f, 0.f, 0.f, 0.f};
  size_t a0 = (size_t)mt0 * 4096 + lane;
  size_t a1 = a0 + 4096;
  size_t b0 = (size_t)nt0 * 4096 + lane;
  size_t b1 = b0 + 4096;
#pragma unroll 2
  for (int kc = 0; kc < 32; ++kc) {
    bf16x8 a0h = Af[a0], a0l = Af[a0 + 64];
    bf16x8 a1h = Af[a1], a1l = Af[a1 + 64];
    bf16x8 b0h = Bf[b0], b0l = Bf[b0 + 64];
    bf16x8 b1h = Bf[b1], b1l = Bf[b1 + 64];
    a0 += 128; a1 += 128; b0 += 128; b1 += 128;
    acc00 = MFMA16(a0h, b0h, acc00);
    acc00 = MFMA16(a0l, b0h, acc00);
    acc00 = MFMA16(a0h, b0l, acc00);
    acc01 = MFMA16(a0h, b1h, acc01);
    acc01 = MFMA16(a0l, b1h, acc01);
    acc01 = MFMA16(a0h, b1l, acc01);
    acc10 = MFMA16(a1h, b0h, acc10);
    acc10 = MFMA16(a1l, b0h, acc10);
    acc10 = MFMA16(a1h, b0l, acc10);
    acc11 = MFMA16(a1h, b1h, acc11);
    acc11 = MFMA16(a1l, b1h, acc11);
    acc11 = MFMA16(a1h, b1l, acc11);
  }
  const int col = nt0 * 16 + (lane & 15);
  const int r0 = mt0 * 16 + ((lane >> 4) << 2);
#pragma unroll
  for (int reg = 0; reg < 4; ++reg) {
    int r = r0 + reg;
    if (r < M) {
      C[(size_t)r * N + col] = acc00[reg] * scale;
      C[(size_t)r * N + col + 16] = acc01[reg] * scale;
    }
    if (r + 16 < M) {
      C[(size_t)(r + 16) * N + col] = acc10[reg] * scale;
      C[(size_t)(r + 16) * N + col + 16] = acc11[reg] * scale;
    }
  }
}

// ---------------- per-batch Gram matrices ----------------
__global__ __launch_bounds__(256) void gram_kernel(const float* __restrict__ V,
                                                   float* __restrict__ out, int Nrows) {
  const int blk = blockIdx.x;
  const float* base = V + (size_t)blk * Nrows * D;
  __shared__ float vs[36 * 65];
  const int t = threadIdx.x;
  const int NN = Nrows * Nrows;
  int io[6], jo[6];
#pragma unroll
  for (int oi = 0; oi < 6; ++oi) {
    int o = t + oi * 256;
    io[oi] = o / Nrows;
    jo[oi] = o - io[oi] * Nrows;
  }
  float acc[6] = {0.f, 0.f, 0.f, 0.f, 0.f, 0.f};
  for (int c = 0; c < 16; ++c) {
    for (int idx = t; idx < Nrows * 64; idx += 256) {
      int row = idx >> 6, kk = idx & 63;
      vs[row * 65 + kk] = base[(size_t)row * D + c * 64 + kk];
    }
    __syncthreads();
#pragma unroll
    for (int oi = 0; oi < 6; ++oi) {
      int o = t + oi * 256;
      if (o < NN) {
        const float* vi = &vs[io[oi] * 65];
        const float* vj = &vs[jo[oi] * 65];
        float x = acc[oi];
#pragma unroll 8
        for (int kk = 0; kk < 64; ++kk) x = fmaf(vi[kk], vj[kk], x);
        acc[oi] = x;
      }
    }
    __syncthreads();
  }
  for (int oi = 0; oi < 6; ++oi) {
    int o = t + oi * 256;
    if (o < NN) out[(size_t)blk * NN + o] = acc[oi];
  }
}

// ---------------- per-(a,b) pair kernel: MFMA hidden layers ----------------
__global__ __launch_bounds__(256) void pair_kernel(
    const float* __restrict__ Sb, const float* __restrict__ Cb,
    const bf16x8* __restrict__ G2aF, const bf16x8* __restrict__ G1bF,
    const float* __restrict__ g22, const float* __restrict__ g11,
    const float* __restrict__ b1a, const float* __restrict__ w2a, const float* __restrict__ b2a,
    const float* __restrict__ b1b, const float* __restrict__ w2b, const float* __restrict__ b2b,
    float* __restrict__ out) {
  const int pair = blockIdx.x;
  const int a = pair / NB2;
  const int b = pair - a * NB2;
  const int t = threadIdx.x, lane = t & 63, w = t >> 6;
  const int c16 = lane & 15, q = lane >> 4;

  __shared__ __align__(16) float sS[LL][RR];
  __shared__ __align__(16) float p2s[48][36];   // rows r (36..47 zero), cols l (30..35 zero)
  __shared__ __align__(16) float p1s[32][68];   // rows l (30,31 zero), cols r (36..67 zero)
  __shared__ float red[4][48][NH];
  __shared__ float sa[RR][NH];
  __shared__ float sbm[LL][NH];
  __shared__ float qa[RR], qb[LL], u1[RR], u2[LL];
  __shared__ float redbuf[3][4];

  for (int i = t; i < 48 * 36; i += 256) ((float*)p2s)[i] = 0.f;
  for (int i = t; i < 32 * 68; i += 256) ((float*)p1s)[i] = 0.f;
  for (int i = t; i < LL * RR; i += 256) {
    int l = i / RR, r = i - l * RR;
    sS[l][r] = Sb[(size_t)(b * LL + l) * 1728 + a * RR + r];
  }
  __syncthreads();

  // softmaxes: p1 over r per l-row; p2 over l per r-column
  if (t < LL) {
    float m = -1e30f;
    for (int r = 0; r < RR; ++r) m = fmaxf(m, sS[t][r]);
    float s = 0.f;
    for (int r = 0; r < RR; ++r) { float e = __expf(sS[t][r] - m); p1s[t][r] = e; s += e; }
    float inv = 1.f / s;
    for (int r = 0; r < RR; ++r) p1s[t][r] *= inv;
  } else if (t >= 64 && t < 64 + RR) {
    int r = t - 64;
    float m = -1e30f;
    for (int l = 0; l < LL; ++l) m = fmaxf(m, sS[l][r]);
    float s = 0.f;
    for (int l = 0; l < LL; ++l) { float e = __expf(sS[l][r] - m); p2s[r][l] = e; s += e; }
    float inv = 1.f / s;
    for (int l = 0; l < LL; ++l) p2s[r][l] *= inv;
  }
  __syncthreads();

  // ===== direction A: H[r][e] = b1a[e] + sum_l p2[r][l] G2a[b][l][e]; scores via w2a =====
  bf16x8 pAh[3], pAl[3];
#pragma unroll
  for (int mt = 0; mt < 3; ++mt) {
    float v[8];
    const float* rp = &p2s[mt * 16 + c16][q * 8];
    float4 x0 = *(const float4*)rp;
    float4 x1 = *(const float4*)(rp + 4);
    v[0] = x0.x; v[1] = x0.y; v[2] = x0.z; v[3] = x0.w;
    v[4] = x1.x; v[5] = x1.y; v[6] = x1.z; v[7] = x1.w;
    split8(v, pAh[mt], pAl[mt]);
  }
  float scA[3][4][NH];
#pragma unroll
  for (int mt = 0; mt < 3; ++mt)
#pragma unroll
    for (int reg = 0; reg < 4; ++reg)
#pragma unroll
      for (int h = 0; h < NH; ++h) scA[mt][reg][h] = 0.f;

  for (int nt = w; nt < 64; nt += 4) {
    const bf16x8* gp = G2aF + ((size_t)(b * 64 + nt) * 2) * 64 + lane;
    bf16x8 Bh = gp[0], Bl = gp[64];
    const int col = nt * 16 + c16;
    const float bias = b1a[col];
    const float w0 = w2a[col], w1 = w2a[D + col], w2v = w2a[2 * D + col], w3 = w2a[3 * D + col];
#pragma unroll
    for (int mt = 0; mt < 3; ++mt) {
      f32x4 acc = {bias, bias, bias, bias};
      acc = MFMA16(pAh[mt], Bh, acc);
      acc = MFMA16(pAl[mt], Bh, acc);
      acc = MFMA16(pAh[mt], Bl, acc);
#pragma unroll
      for (int reg = 0; reg < 4; ++reg) {
        float hv = fmaxf(acc[reg], 0.f);
        scA[mt][reg][0] = fmaf(hv, w0, scA[mt][reg][0]);
        scA[mt][reg][1] = fmaf(hv, w1, scA[mt][reg][1]);
        scA[mt][reg][2] = fmaf(hv, w2v, scA[mt][reg][2]);
        scA[mt][reg][3] = fmaf(hv, w3, scA[mt][reg][3]);
      }
    }
  }
#pragma unroll
  for (int mt = 0; mt < 3; ++mt)
#pragma unroll
    for (int reg = 0; reg < 4; ++reg)
#pragma unroll
      for (int h = 0; h < NH; ++h) {
        float v = scA[mt][reg][h];
        v += __shfl_xor(v, 1);
        v += __shfl_xor(v, 2);
        v += __shfl_xor(v, 4);
        v += __shfl_xor(v, 8);
        if (c16 == 0) red[w][mt * 16 + q * 4 + reg][h] = v;
      }
  __syncthreads();
  if (t < RR * NH) {
    int r = t >> 2, h = t & 3;
    sa[r][h] = red[0][r][h] + red[1][r][h] + red[2][r][h] + red[3][r][h] + b2a[h];
  }
  __syncthreads();

  // ===== direction B: H[l][e] = b1b[e] + sum_r p1[l][r] G1b[a][r][e]; scores via w2b =====
  bf16x8 pBh[2][2], pBl[2][2];
#pragma unroll
  for (int mt = 0; mt < 2; ++mt)
#pragma unroll
    for (int kc = 0; kc < 2; ++kc) {
      float v[8];
      const float* rp = &p1s[mt * 16 + c16][kc * 32 + q * 8];
      float4 x0 = *(const float4*)rp;
      float4 x1 = *(const float4*)(rp + 4);
      v[0] = x0.x; v[1] = x0.y; v[2] = x0.z; v[3] = x0.w;
      v[4] = x1.x; v[5] = x1.y; v[6] = x1.z; v[7] = x1.w;
      split8(v, pBh[mt][kc], pBl[mt][kc]);
    }
  float scB[2][4][NH];
#pragma unroll
  for (int mt = 0; mt < 2; ++mt)
#pragma unroll
    for (int reg = 0; reg < 4; ++reg)
#pragma unroll
      for (int h = 0; h < NH; ++h) scB[mt][reg][h] = 0.f;

  for (int nt = w; nt < 64; nt += 4) {
    const bf16x8* gp = G1bF + (((size_t)(a * 64 + nt) * 2) * 2) * 64 + lane;
    bf16x8 B0h = gp[0], B0l = gp[64], B1h = gp[128], B1l = gp[192];
    const int col = nt * 16 + c16;
    const float bias = b1b[col];
    const float w0 = w2b[col], w1 = w2b[D + col], w2v = w2b[2 * D + col], w3 = w2b[3 * D + col];
#pragma unroll
    for (int mt = 0; mt < 2; ++mt) {
      f32x4 acc = {bias, bias, bias, bias};
      acc = MFMA16(pBh[mt][0], B0h, acc);
      acc = MFMA16(pBl[mt][0], B0h, acc);
      acc = MFMA16(pBh[mt][0], B0l, acc);
      acc = MFMA16(pBh[mt][1], B1h, acc);
      acc = MFMA16(pBl[mt][1], B1h, acc);
      acc = MFMA16(pBh[mt][1], B1l, acc);
#pragma unroll
      for (int reg = 0; reg < 4; ++reg) {
        float hv = fmaxf(acc[reg], 0.f);
        scB[mt][reg][0] = fmaf(hv, w0, scB[mt][reg][0]);
        scB[mt][reg][1] = fmaf(hv, w1, scB[mt][reg][1]);
        scB[mt][reg][2] = fmaf(hv, w2v, scB[mt][reg][2]);
        scB[mt][reg][3] = fmaf(hv, w3, scB[mt][reg][3]);
      }
    }
  }
#pragma unroll
  for (int mt = 0; mt < 2; ++mt)
#pragma unroll
    for (int reg = 0; reg < 4; ++reg)
#pragma unroll
      for (int h = 0; h < NH; ++h) {
        float v = scB[mt][reg][h];
        v += __shfl_xor(v, 1);
        v += __shfl_xor(v, 2);
        v += __shfl_xor(v, 4);
        v += __shfl_xor(v, 8);
        if (c16 == 0) red[w][mt * 16 + q * 4 + reg][h] = v;
      }
  __syncthreads();
  if (t < LL * NH) {
    int l = t >> 2, h = t & 3;
    sbm[l][h] = red[0][l][h] + red[1][l][h] + red[2][l][h] + red[3][l][h] + b2b[h];
  }
  __syncthreads();

  // per-head softmax over n, mean over heads
  if (t < NH) {
    const int h = t;
    float m = -1e30f;
    for (int r = 0; r < RR; ++r) m = fmaxf(m, sa[r][h]);
    float s = 0.f;
    for (int r = 0; r < RR; ++r) { float e = __expf(sa[r][h] - m); sa[r][h] = e; s += e; }
    float inv = 1.f / s;
    for (int r = 0; r < RR; ++r) sa[r][h] *= inv;
  } else if (t >= 64 && t < 64 + NH) {
    const int h = t - 64;
    float m = -1e30f;
    for (int l = 0; l < LL; ++l) m = fmaxf(m, sbm[l][h]);
    float s = 0.f;
    for (int l = 0; l < LL; ++l) { float e = __expf(sbm[l][h] - m); sbm[l][h] = e; s += e; }
    float inv = 1.f / s;
    for (int l = 0; l < LL; ++l) sbm[l][h] *= inv;
  }
  __syncthreads();
  if (t < RR) qa[t] = 0.25f * (sa[t][0] + sa[t][1] + sa[t][2] + sa[t][3]);
  else if (t >= 64 && t < 64 + LL) {
    int l = t - 64;
    qb[l] = 0.25f * (sbm[l][0] + sbm[l][1] + sbm[l][2] + sbm[l][3]);
  }
  __syncthreads();

  if (t < LL) {
    float x = 0.f;
    for (int r = 0; r < RR; ++r) x = fmaf(qa[r], p2s[r][t], x);
    u2[t] = x;
  } else if (t >= 64 && t < 64 + RR) {
    int r = t - 64;
    float x = 0.f;
    for (int l = 0; l < LL; ++l) x = fmaf(qb[l], p1s[l][r], x);
    u1[r] = x;
  }
  __syncthreads();

  float pnum = 0.f, pn1 = 0.f, pn2 = 0.f;
  {
    const float* Cab = Cb + (size_t)(b * LL) * 1728 + a * RR;
    for (int i = t; i < LL * RR; i += 256) {
      int l = i / RR, r = i - l * RR;
      pnum = fmaf(u2[l] * u1[r], Cab[(size_t)l * 1728 + r], pnum);
    }
    const float* G22 = g22 + (size_t)b * LL * LL;
    for (int i = t; i < LL * LL; i += 256) {
      int l = i / LL, l2 = i - l * LL;
      pn1 = fmaf(u2[l] * u2[l2], G22[i], pn1);
    }
    const float* G11 = g11 + (size_t)a * RR * RR;
    for (int i = t; i < RR * RR; i += 256) {
      int r = i / RR, r2 = i - r * RR;
      pn2 = fmaf(u1[r] * u1[r2], G11[i], pn2);
    }
  }
#pragma unroll
  for (int off = 32; off > 0; off >>= 1) {
    pnum += __shfl_down(pnum, off);
    pn1  += __shfl_down(pn1, off);
    pn2  += __shfl_down(pn2, off);
  }
  if ((t & 63) == 0) { redbuf[0][w] = pnum; redbuf[1][w] = pn1; redbuf[2][w] = pn2; }
  __syncthreads();
  if (t == 0) {
    float num = redbuf[0][0] + redbuf[0][1] + redbuf[0][2] + redbuf[0][3];
    float n1s = redbuf[1][0] + redbuf[1][1] + redbuf[1][2] + redbuf[1][3];
    float n2s = redbuf[2][0] + redbuf[2][1] + redbuf[2][2] + redbuf[2][3];
    float n1 = sqrtf(fmaxf(n1s, 0.f));
    float n2 = sqrtf(fmaxf(n2s, 0.f));
    out[pair] = num / ((n1 + 1e-8f) * (n2 + 1e-8f));
  }
}

extern "C" void kernel_launch(void* const* d_in, const int* in_sizes, int n_in,
                              void* d_out, int out_size, void* d_ws, size_t ws_size,
                              hipStream_t stream) {
  const float* v1    = (const float*)d_in[0];
  const float* v2    = (const float*)d_in[1];
  const float* w_img = (const float*)d_in[2];
  const float* w_txt = (const float*)d_in[3];
  const float* w1a   = (const float*)d_in[4];
  const float* b1a   = (const float*)d_in[5];
  const float* w2a   = (const float*)d_in[6];
  const float* b2a   = (const float*)d_in[7];
  const float* w1b   = (const float*)d_in[8];
  const float* b1b   = (const float*)d_in[9];
  const float* w2b   = (const float*)d_in[10];
  const float* b2b   = (const float*)d_in[11];
  float* out = (float*)d_out;

  // fp32 region
  float* ws   = (float*)d_ws;
  float* k1   = ws;                           // 1728*1024
  float* k2   = k1 + (size_t)1728 * 1024;     // 1440*1024
  float* G2a  = k2 + (size_t)1440 * 1024;     // 1440*1024
  float* G1b  = G2a + (size_t)1440 * 1024;    // 1728*1024
  float* Sbuf = G1b + (size_t)1728 * 1024;    // 1440*1728
  float* Cbuf = Sbuf + (size_t)1440 * 1728;   // 1440*1728
  float* g22  = Cbuf + (size_t)1440 * 1728;   // 48*900
  float* g11  = g22 + (size_t)48 * 900;       // 48*1296

  // split-bf16 fragment region
  unsigned short* fb    = (unsigned short*)(g11 + (size_t)48 * 1296);
  unsigned short* v1f   = fb;                                  // 108 tiles
  unsigned short* v2f   = v1f + (size_t)108 * 32768;           //  92 tiles
  unsigned short* k1f   = v2f + (size_t)92 * 32768;            // 108 tiles
  unsigned short* k2f   = k1f + (size_t)108 * 32768;           //  92 tiles
  unsigned short* wimgf = k2f + (size_t)92 * 32768;            //  64 tiles each
  unsigned short* wtxtf = wimgf + (size_t)64 * 32768;
  unsigned short* w1af  = wtxtf + (size_t)64 * 32768;
  unsigned short* w1bf  = w1af + (size_t)64 * 32768;
  unsigned short* G2aF  = w1bf + (size_t)64 * 32768;           // 48 * 65536 ush
  unsigned short* G1bF  = G2aF + (size_t)48 * 65536;           // 48 * 131072 ush

  convert_frag<<<108 * 8, 256, 0, stream>>>(v1, v1f, 1728);
  convert_frag<<< 92 * 8, 256, 0, stream>>>(v2, v2f, 1440);
  convert_frag<<< 64 * 8, 256, 0, stream>>>(w_img, wimgf, 1024);
  convert_frag<<< 64 * 8, 256, 0, stream>>>(w_txt, wtxtf, 1024);
  convert_frag<<< 64 * 8, 256, 0, stream>>>(w1a, w1af, 1024);
  convert_frag<<< 64 * 8, 256, 0, stream>>>(w1b, w1bf, 1024);

  mfma_gemm_abt<<<dim3(16, 27), 256, 0, stream>>>((const bf16x8*)v1f, (const bf16x8*)wimgf, k1, 1728, 1024, 1.f);
  mfma_gemm_abt<<<dim3(16, 23), 256, 0, stream>>>((const bf16x8*)v2f, (const bf16x8*)wtxtf, k2, 1440, 1024, 1.f);
  mfma_gemm_abt<<<dim3(16, 23), 256, 0, stream>>>((const bf16x8*)v2f, (const bf16x8*)w1af, G2a, 1440, 1024, 1.f);
  mfma_gemm_abt<<<dim3(16, 27), 256, 0, stream>>>((const bf16x8*)v1f, (const bf16x8*)w1bf, G1b, 1728, 1024, 1.f);

  convert_frag<<<108 * 8, 256, 0, stream>>>(k1, k1f, 1728);
  convert_frag<<< 92 * 8, 256, 0, stream>>>(k2, k2f, 1440);
  conv_g2a<<<48 * 16, 256, 0, stream>>>(G2a, G2aF);
  conv_g1b<<<48 * 16, 256, 0, stream>>>(G1b, G1bF);

  mfma_gemm_abt<<<dim3(27, 23), 256, 0, stream>>>((const bf16x8*)k2f, (const bf16x8*)k1f, Sbuf, 1440, 1728, 0.03125f);
  mfma_gemm_abt<<<dim3(27, 23), 256, 0, stream>>>((const bf16x8*)v2f, (const bf16x8*)v1f, Cbuf, 1440, 1728, 1.f);

  gram_kernel<<<48, 256, 0, stream>>>(v1, g11, 36);
  gram_kernel<<<48, 256, 0, stream>>>(v2, g22, 30);

  pair_kernel<<<2304, 256, 0, stream>>>(Sbuf, Cbuf, (const bf16x8*)G2aF, (const bf16x8*)G1bF,
                                        g22, g11, b1a, w2a, b2a, b1b, w2b, b2b, out);
}

// Round 4
// 339.690 us; speedup vs baseline: 3.0592x; 1.6045x over previous
//
#include <hip/hip_runtime.h>

#define D 1024
#define NB1 48
#define NB2 48
#define RR 36
#define LL 30
#define NH 4

typedef short bf16x8 __attribute__((ext_vector_type(8)));
typedef float f32x4 __attribute__((ext_vector_type(4)));
typedef unsigned short u16x8 __attribute__((ext_vector_type(8)));

#define MFMA16(a, b, c) __builtin_amdgcn_mfma_f32_16x16x32_bf16(a, b, c, 0, 0, 0)

__device__ __forceinline__ unsigned short f2bf(float x) {
  unsigned u = __float_as_uint(x);
  u += 0x7FFF + ((u >> 16) & 1);
  return (unsigned short)(u >> 16);
}
__device__ __forceinline__ float bf2f(unsigned short h) {
  return __uint_as_float(((unsigned)h) << 16);
}
__device__ __forceinline__ void split8(const float* v, bf16x8& h8, bf16x8& l8) {
  u16x8 hi, lo;
#pragma unroll
  for (int i = 0; i < 8; ++i) {
    unsigned short h = f2bf(v[i]);
    hi[i] = h;
    lo[i] = f2bf(v[i] - bf2f(h));
  }
  h8 = __builtin_bit_cast(bf16x8, hi);
  l8 = __builtin_bit_cast(bf16x8, lo);
}

// ---- fp32 row-major (rows x 1024) -> split-bf16 MFMA fragment layout ----
__device__ __forceinline__ void conv_body(const float* __restrict__ X,
                                          unsigned short* __restrict__ out,
                                          int rows, int g) {
  const int lane = threadIdx.x & 63;
  const int tile = g >> 5, kc = g & 31;
  const int row = tile * 16 + (lane & 15);
  const int k = kc * 32 + (lane >> 4) * 8;
  float v[8];
  if (row < rows) {
    const float4* s = (const float4*)(X + (size_t)row * 1024 + k);
    float4 x0 = s[0], x1 = s[1];
    v[0] = x0.x; v[1] = x0.y; v[2] = x0.z; v[3] = x0.w;
    v[4] = x1.x; v[5] = x1.y; v[6] = x1.z; v[7] = x1.w;
  } else {
#pragma unroll
    for (int i = 0; i < 8; ++i) v[i] = 0.f;
  }
  bf16x8 hi, lo;
  split8(v, hi, lo);
  bf16x8* o = (bf16x8*)(out + (size_t)g * 1024 + lane * 8);
  o[0] = hi;
  o[64] = lo;
}

// 6 input matrices in one launch. grid (864, 6)
__global__ __launch_bounds__(256) void conv6(
    const float* __restrict__ v1, const float* __restrict__ v2,
    const float* __restrict__ wimg, const float* __restrict__ wtxt,
    const float* __restrict__ w1a, const float* __restrict__ w1b,
    unsigned short* v1f, unsigned short* v2f, unsigned short* wimgf,
    unsigned short* wtxtf, unsigned short* w1af, unsigned short* w1bf) {
  const float* X; unsigned short* O; int rows;
  switch (blockIdx.y) {
    case 0: X = v1; O = v1f; rows = 1728; break;
    case 1: X = v2; O = v2f; rows = 1440; break;
    case 2: X = wimg; O = wimgf; rows = 1024; break;
    case 3: X = wtxt; O = wtxtf; rows = 1024; break;
    case 4: X = w1a; O = w1af; rows = 1024; break;
    default: X = w1b; O = w1bf; rows = 1024; break;
  }
  const int tiles = (rows + 15) >> 4;
  const int g = blockIdx.x * 4 + (threadIdx.x >> 6);
  if (g >= tiles * 32) return;
  conv_body(X, O, rows, g);
}

// k1 (1728) / k2 (1440). grid (864, 2)
__global__ __launch_bounds__(256) void conv_k(const float* __restrict__ k1,
                                              const float* __restrict__ k2,
                                              unsigned short* k1f, unsigned short* k2f) {
  const float* X = blockIdx.y ? k2 : k1;
  unsigned short* O = blockIdx.y ? k2f : k1f;
  const int rows = blockIdx.y ? 1440 : 1728;
  const int tiles = (rows + 15) >> 4;
  const int g = blockIdx.x * 4 + (threadIdx.x >> 6);
  if (g >= tiles * 32) return;
  conv_body(X, O, rows, g);
}

// G2a -> B-frag [b][nt(64)][part(2)][512] ; G1b -> [a][nt(64)][kc(2)][part(2)][512]
// grid (768, 2)
__global__ __launch_bounds__(256) void convG(const float* __restrict__ G2a,
                                             const float* __restrict__ G1b,
                                             unsigned short* G2aF, unsigned short* G1bF) {
  const int t = threadIdx.x, lane = t & 63;
  const int bb = blockIdx.x >> 4;
  const int nt = ((blockIdx.x & 15) << 2) + (t >> 6);
  const int c = lane & 15, q = lane >> 4;
  if (blockIdx.y == 0) {
    float v[8];
#pragma unroll
    for (int j = 0; j < 8; ++j) {
      int l = q * 8 + j;
      v[j] = (l < LL) ? G2a[(size_t)(bb * LL + l) * D + nt * 16 + c] : 0.f;
    }
    bf16x8 hi, lo;
    split8(v, hi, lo);
    bf16x8* o = (bf16x8*)(G2aF + ((size_t)(bb * 64 + nt) * 2) * 512 + lane * 8);
    o[0] = hi;
    o[64] = lo;
  } else {
#pragma unroll
    for (int kc = 0; kc < 2; ++kc) {
      float v[8];
#pragma unroll
      for (int j = 0; j < 8; ++j) {
        int r = kc * 32 + q * 8 + j;
        v[j] = (r < RR) ? G1b[(size_t)(bb * RR + r) * D + nt * 16 + c] : 0.f;
      }
      bf16x8 hi, lo;
      split8(v, hi, lo);
      bf16x8* o = (bf16x8*)(G1bF + (((size_t)(bb * 64 + nt) * 2 + kc) * 2) * 512 + lane * 8);
      o[0] = hi;
      o[64] = lo;
    }
  }
}

// ---- split-bf16 MFMA GEMM core: each wave 4x4 16-tiles, direct frag loads ----
__device__ __forceinline__ void gemm4_body(const bf16x8* __restrict__ Af,
                                           const bf16x8* __restrict__ Bf,
                                           float* __restrict__ C,
                                           int M, int N, float scale,
                                           int Mtiles, int Ntiles) {
  const int lane = threadIdx.x & 63;
  const int w = threadIdx.x >> 6;
  const int mb = blockIdx.y * 8 + (w >> 1) * 4;
  const int nb = blockIdx.x * 8 + (w & 1) * 4;
  size_t ab[4], bb[4];
#pragma unroll
  for (int i = 0; i < 4; ++i) {
    int tm = mb + i; if (tm > Mtiles - 1) tm = Mtiles - 1;
    ab[i] = (size_t)tm * 4096 + lane;
    int tn = nb + i; if (tn > Ntiles - 1) tn = Ntiles - 1;
    bb[i] = (size_t)tn * 4096 + lane;
  }
  f32x4 acc[4][4];
#pragma unroll
  for (int i = 0; i < 4; ++i)
#pragma unroll
    for (int j = 0; j < 4; ++j) acc[i][j] = (f32x4){0.f, 0.f, 0.f, 0.f};
#pragma unroll 1
  for (int kc = 0; kc < 32; ++kc) {
    bf16x8 ah[4], al[4], bh[4], bl[4];
#pragma unroll
    for (int i = 0; i < 4; ++i) { ah[i] = Af[ab[i]]; al[i] = Af[ab[i] + 64]; ab[i] += 128; }
#pragma unroll
    for (int j = 0; j < 4; ++j) { bh[j] = Bf[bb[j]]; bl[j] = Bf[bb[j] + 64]; bb[j] += 128; }
#pragma unroll
    for (int i = 0; i < 4; ++i)
#pragma unroll
      for (int j = 0; j < 4; ++j) {
        acc[i][j] = MFMA16(ah[i], bh[j], acc[i][j]);
        acc[i][j] = MFMA16(al[i], bh[j], acc[i][j]);
        acc[i][j] = MFMA16(ah[i], bl[j], acc[i][j]);
      }
  }
  const int c16 = lane & 15, q = lane >> 4;
#pragma unroll
  for (int i = 0; i < 4; ++i) {
#pragma unroll
    for (int reg = 0; reg < 4; ++reg) {
      int r = (mb + i) * 16 + q * 4 + reg;
      if (r < M) {
#pragma unroll
        for (int j = 0; j < 4; ++j) {
          int col = (nb + j) * 16 + c16;
          if (col < N) C[(size_t)r * N + col] = acc[i][j][reg] * scale;
        }
      }
    }
  }
}

// 4 projection GEMMs in one launch. grid (8, 14, 4)
__global__ __launch_bounds__(256) void proj_fused(
    const bf16x8* __restrict__ v1f, const bf16x8* __restrict__ v2f,
    const bf16x8* __restrict__ wimgf, const bf16x8* __restrict__ wtxtf,
    const bf16x8* __restrict__ w1af, const bf16x8* __restrict__ w1bf,
    float* k1, float* k2, float* G2a, float* G1b) {
  const int z = blockIdx.z;
  const bf16x8* Af = (z == 0 || z == 3) ? v1f : v2f;
  const bf16x8* Bf = (z == 0) ? wimgf : (z == 1) ? wtxtf : (z == 2) ? w1af : w1bf;
  float* C = (z == 0) ? k1 : (z == 1) ? k2 : (z == 2) ? G2a : G1b;
  const int M = (z == 0 || z == 3) ? 1728 : 1440;
  const int Mt = (z == 0 || z == 3) ? 108 : 92;
  if ((int)blockIdx.y * 8 >= Mt) return;
  gemm4_body(Af, Bf, C, M, 1024, 1.f, Mt, 64);
}

// 2 cross GEMMs in one launch. grid (14, 12, 2)
__global__ __launch_bounds__(256) void cross_fused(
    const bf16x8* __restrict__ k2f, const bf16x8* __restrict__ k1f,
    const bf16x8* __restrict__ v2f, const bf16x8* __restrict__ v1f,
    float* Sbuf, float* Cbuf) {
  if (blockIdx.z == 0) gemm4_body(k2f, k1f, Sbuf, 1440, 1728, 0.03125f, 92, 108);
  else                 gemm4_body(v2f, v1f, Cbuf, 1440, 1728, 1.f, 92, 108);
}

// ---- Gram partials: grid (8, 96); y<48 -> v1 batch (36 rows), else v2 (30) ----
__global__ __launch_bounds__(256) void gram_partial(const float* __restrict__ v1,
                                                    const float* __restrict__ v2,
                                                    float* __restrict__ pg) {
  const int y = blockIdx.y, cx = blockIdx.x;
  const int isV1 = y < 48;
  const int batch = isV1 ? y : y - 48;
  const int Nr = isV1 ? RR : LL;
  const float* base = isV1 ? v1 + (size_t)batch * RR * D : v2 + (size_t)batch * LL * D;
  __shared__ __align__(16) float vs[36][132];
  const int t = threadIdx.x;
  for (int idx = t; idx < Nr * 32; idx += 256) {
    int row = idx >> 5, c4 = idx & 31;
    *(float4*)&vs[row][c4 * 4] = *(const float4*)&base[(size_t)row * D + cx * 128 + c4 * 4];
  }
  __syncthreads();
  const int nt3 = Nr / 3;                 // 12 or 10
  float acc[3][3] = {{0.f,0.f,0.f},{0.f,0.f,0.f},{0.f,0.f,0.f}};
  const int i0 = (t / nt3) * 3, j0 = (t - (t / nt3) * nt3) * 3;
  if (t < nt3 * nt3) {
    for (int k4 = 0; k4 < 32; ++k4) {
      float4 a[3], b[3];
#pragma unroll
      for (int ii = 0; ii < 3; ++ii) a[ii] = *(const float4*)&vs[i0 + ii][k4 * 4];
#pragma unroll
      for (int jj = 0; jj < 3; ++jj) b[jj] = *(const float4*)&vs[j0 + jj][k4 * 4];
#pragma unroll
      for (int ii = 0; ii < 3; ++ii)
#pragma unroll
        for (int jj = 0; jj < 3; ++jj) {
          acc[ii][jj] = fmaf(a[ii].x, b[jj].x, acc[ii][jj]);
          acc[ii][jj] = fmaf(a[ii].y, b[jj].y, acc[ii][jj]);
          acc[ii][jj] = fmaf(a[ii].z, b[jj].z, acc[ii][jj]);
          acc[ii][jj] = fmaf(a[ii].w, b[jj].w, acc[ii][jj]);
        }
    }
    float* o = pg + ((size_t)y * 8 + cx) * 1296;
#pragma unroll
    for (int ii = 0; ii < 3; ++ii)
#pragma unroll
      for (int jj = 0; jj < 3; ++jj) o[(i0 + ii) * Nr + (j0 + jj)] = acc[ii][jj];
  }
}

__global__ __launch_bounds__(256) void gram_reduce(const float* __restrict__ pg,
                                                   float* __restrict__ g11,
                                                   float* __restrict__ g22) {
  const int y = blockIdx.x;
  const int isV1 = y < 48;
  const int batch = isV1 ? y : y - 48;
  const int NN = isV1 ? RR * RR : LL * LL;
  const float* p = pg + (size_t)y * 8 * 1296;
  float* o = isV1 ? g11 + (size_t)batch * RR * RR : g22 + (size_t)batch * LL * LL;
  for (int i = threadIdx.x; i < NN; i += 256) {
    float s = 0.f;
#pragma unroll
    for (int c = 0; c < 8; ++c) s += p[c * 1296 + i];
    o[i] = s;
  }
}

// ---------------- per-(a,b) pair kernel (unchanged from round 3) ----------------
__global__ __launch_bounds__(256) void pair_kernel(
    const float* __restrict__ Sb, const float* __restrict__ Cb,
    const bf16x8* __restrict__ G2aF, const bf16x8* __restrict__ G1bF,
    const float* __restrict__ g22, const float* __restrict__ g11,
    const float* __restrict__ b1a, const float* __restrict__ w2a, const float* __restrict__ b2a,
    const float* __restrict__ b1b, const float* __restrict__ w2b, const float* __restrict__ b2b,
    float* __restrict__ out) {
  const int pair = blockIdx.x;
  const int a = pair / NB2;
  const int b = pair - a * NB2;
  const int t = threadIdx.x, lane = t & 63, w = t >> 6;
  const int c16 = lane & 15, q = lane >> 4;

  __shared__ __align__(16) float sS[LL][RR];
  __shared__ __align__(16) float p2s[48][36];
  __shared__ __align__(16) float p1s[32][68];
  __shared__ float red[4][48][NH];
  __shared__ float sa[RR][NH];
  __shared__ float sbm[LL][NH];
  __shared__ float qa[RR], qb[LL], u1[RR], u2[LL];
  __shared__ float redbuf[3][4];

  for (int i = t; i < 48 * 36; i += 256) ((float*)p2s)[i] = 0.f;
  for (int i = t; i < 32 * 68; i += 256) ((float*)p1s)[i] = 0.f;
  for (int i = t; i < LL * RR; i += 256) {
    int l = i / RR, r = i - l * RR;
    sS[l][r] = Sb[(size_t)(b * LL + l) * 1728 + a * RR + r];
  }
  __syncthreads();

  if (t < LL) {
    float m = -1e30f;
    for (int r = 0; r < RR; ++r) m = fmaxf(m, sS[t][r]);
    float s = 0.f;
    for (int r = 0; r < RR; ++r) { float e = __expf(sS[t][r] - m); p1s[t][r] = e; s += e; }
    float inv = 1.f / s;
    for (int r = 0; r < RR; ++r) p1s[t][r] *= inv;
  } else if (t >= 64 && t < 64 + RR) {
    int r = t - 64;
    float m = -1e30f;
    for (int l = 0; l < LL; ++l) m = fmaxf(m, sS[l][r]);
    float s = 0.f;
    for (int l = 0; l < LL; ++l) { float e = __expf(sS[l][r] - m); p2s[r][l] = e; s += e; }
    float inv = 1.f / s;
    for (int l = 0; l < LL; ++l) p2s[r][l] *= inv;
  }
  __syncthreads();

  // direction A
  bf16x8 pAh[3], pAl[3];
#pragma unroll
  for (int mt = 0; mt < 3; ++mt) {
    float v[8];
    const float* rp = &p2s[mt * 16 + c16][q * 8];
    float4 x0 = *(const float4*)rp;
    float4 x1 = *(const float4*)(rp + 4);
    v[0] = x0.x; v[1] = x0.y; v[2] = x0.z; v[3] = x0.w;
    v[4] = x1.x; v[5] = x1.y; v[6] = x1.z; v[7] = x1.w;
    split8(v, pAh[mt], pAl[mt]);
  }
  float scA[3][4][NH];
#pragma unroll
  for (int mt = 0; mt < 3; ++mt)
#pragma unroll
    for (int reg = 0; reg < 4; ++reg)
#pragma unroll
      for (int h = 0; h < NH; ++h) scA[mt][reg][h] = 0.f;

  for (int nt = w; nt < 64; nt += 4) {
    const bf16x8* gp = G2aF + ((size_t)(b * 64 + nt) * 2) * 64 + lane;
    bf16x8 Bh = gp[0], Bl = gp[64];
    const int col = nt * 16 + c16;
    const float bias = b1a[col];
    const float w0 = w2a[col], w1 = w2a[D + col], w2v = w2a[2 * D + col], w3 = w2a[3 * D + col];
#pragma unroll
    for (int mt = 0; mt < 3; ++mt) {
      f32x4 acc = {bias, bias, bias, bias};
      acc = MFMA16(pAh[mt], Bh, acc);
      acc = MFMA16(pAl[mt], Bh, acc);
      acc = MFMA16(pAh[mt], Bl, acc);
#pragma unroll
      for (int reg = 0; reg < 4; ++reg) {
        float hv = fmaxf(acc[reg], 0.f);
        scA[mt][reg][0] = fmaf(hv, w0, scA[mt][reg][0]);
        scA[mt][reg][1] = fmaf(hv, w1, scA[mt][reg][1]);
        scA[mt][reg][2] = fmaf(hv, w2v, scA[mt][reg][2]);
        scA[mt][reg][3] = fmaf(hv, w3, scA[mt][reg][3]);
      }
    }
  }
#pragma unroll
  for (int mt = 0; mt < 3; ++mt)
#pragma unroll
    for (int reg = 0; reg < 4; ++reg)
#pragma unroll
      for (int h = 0; h < NH; ++h) {
        float v = scA[mt][reg][h];
        v += __shfl_xor(v, 1);
        v += __shfl_xor(v, 2);
        v += __shfl_xor(v, 4);
        v += __shfl_xor(v, 8);
        if (c16 == 0) red[w][mt * 16 + q * 4 + reg][h] = v;
      }
  __syncthreads();
  if (t < RR * NH) {
    int r = t >> 2, h = t & 3;
    sa[r][h] = red[0][r][h] + red[1][r][h] + red[2][r][h] + red[3][r][h] + b2a[h];
  }
  __syncthreads();

  // direction B
  bf16x8 pBh[2][2], pBl[2][2];
#pragma unroll
  for (int mt = 0; mt < 2; ++mt)
#pragma unroll
    for (int kc = 0; kc < 2; ++kc) {
      float v[8];
      const float* rp = &p1s[mt * 16 + c16][kc * 32 + q * 8];
      float4 x0 = *(const float4*)rp;
      float4 x1 = *(const float4*)(rp + 4);
      v[0] = x0.x; v[1] = x0.y; v[2] = x0.z; v[3] = x0.w;
      v[4] = x1.x; v[5] = x1.y; v[6] = x1.z; v[7] = x1.w;
      split8(v, pBh[mt][kc], pBl[mt][kc]);
    }
  float scB[2][4][NH];
#pragma unroll
  for (int mt = 0; mt < 2; ++mt)
#pragma unroll
    for (int reg = 0; reg < 4; ++reg)
#pragma unroll
      for (int h = 0; h < NH; ++h) scB[mt][reg][h] = 0.f;

  for (int nt = w; nt < 64; nt += 4) {
    const bf16x8* gp = G1bF + (((size_t)(a * 64 + nt) * 2) * 2) * 64 + lane;
    bf16x8 B0h = gp[0], B0l = gp[64], B1h = gp[128], B1l = gp[192];
    const int col = nt * 16 + c16;
    const float bias = b1b[col];
    const float w0 = w2b[col], w1 = w2b[D + col], w2v = w2b[2 * D + col], w3 = w2b[3 * D + col];
#pragma unroll
    for (int mt = 0; mt < 2; ++mt) {
      f32x4 acc = {bias, bias, bias, bias};
      acc = MFMA16(pBh[mt][0], B0h, acc);
      acc = MFMA16(pBl[mt][0], B0h, acc);
      acc = MFMA16(pBh[mt][0], B0l, acc);
      acc = MFMA16(pBh[mt][1], B1h, acc);
      acc = MFMA16(pBl[mt][1], B1h, acc);
      acc = MFMA16(pBh[mt][1], B1l, acc);
#pragma unroll
      for (int reg = 0; reg < 4; ++reg) {
        float hv = fmaxf(acc[reg], 0.f);
        scB[mt][reg][0] = fmaf(hv, w0, scB[mt][reg][0]);
        scB[mt][reg][1] = fmaf(hv, w1, scB[mt][reg][1]);
        scB[mt][reg][2] = fmaf(hv, w2v, scB[mt][reg][2]);
        scB[mt][reg][3] = fmaf(hv, w3, scB[mt][reg][3]);
      }
    }
  }
#pragma unroll
  for (int mt = 0; mt < 2; ++mt)
#pragma unroll
    for (int reg = 0; reg < 4; ++reg)
#pragma unroll
      for (int h = 0; h < NH; ++h) {
        float v = scB[mt][reg][h];
        v += __shfl_xor(v, 1);
        v += __shfl_xor(v, 2);
        v += __shfl_xor(v, 4);
        v += __shfl_xor(v, 8);
        if (c16 == 0) red[w][mt * 16 + q * 4 + reg][h] = v;
      }
  __syncthreads();
  if (t < LL * NH) {
    int l = t >> 2, h = t & 3;
    sbm[l][h] = red[0][l][h] + red[1][l][h] + red[2][l][h] + red[3][l][h] + b2b[h];
  }
  __syncthreads();

  if (t < NH) {
    const int h = t;
    float m = -1e30f;
    for (int r = 0; r < RR; ++r) m = fmaxf(m, sa[r][h]);
    float s = 0.f;
    for (int r = 0; r < RR; ++r) { float e = __expf(sa[r][h] - m); sa[r][h] = e; s += e; }
    float inv = 1.f / s;
    for (int r = 0; r < RR; ++r) sa[r][h] *= inv;
  } else if (t >= 64 && t < 64 + NH) {
    const int h = t - 64;
    float m = -1e30f;
    for (int l = 0; l < LL; ++l) m = fmaxf(m, sbm[l][h]);
    float s = 0.f;
    for (int l = 0; l < LL; ++l) { float e = __expf(sbm[l][h] - m); sbm[l][h] = e; s += e; }
    float inv = 1.f / s;
    for (int l = 0; l < LL; ++l) sbm[l][h] *= inv;
  }
  __syncthreads();
  if (t < RR) qa[t] = 0.25f * (sa[t][0] + sa[t][1] + sa[t][2] + sa[t][3]);
  else if (t >= 64 && t < 64 + LL) {
    int l = t - 64;
    qb[l] = 0.25f * (sbm[l][0] + sbm[l][1] + sbm[l][2] + sbm[l][3]);
  }
  __syncthreads();

  if (t < LL) {
    float x = 0.f;
    for (int r = 0; r < RR; ++r) x = fmaf(qa[r], p2s[r][t], x);
    u2[t] = x;
  } else if (t >= 64 && t < 64 + RR) {
    int r = t - 64;
    float x = 0.f;
    for (int l = 0; l < LL; ++l) x = fmaf(qb[l], p1s[l][r], x);
    u1[r] = x;
  }
  __syncthreads();

  float pnum = 0.f, pn1 = 0.f, pn2 = 0.f;
  {
    const float* Cab = Cb + (size_t)(b * LL) * 1728 + a * RR;
    for (int i = t; i < LL * RR; i += 256) {
      int l = i / RR, r = i - l * RR;
      pnum = fmaf(u2[l] * u1[r], Cab[(size_t)l * 1728 + r], pnum);
    }
    const float* G22 = g22 + (size_t)b * LL * LL;
    for (int i = t; i < LL * LL; i += 256) {
      int l = i / LL, l2 = i - l * LL;
      pn1 = fmaf(u2[l] * u2[l2], G22[i], pn1);
    }
    const float* G11 = g11 + (size_t)a * RR * RR;
    for (int i = t; i < RR * RR; i += 256) {
      int r = i / RR, r2 = i - r * RR;
      pn2 = fmaf(u1[r] * u1[r2], G11[i], pn2);
    }
  }
#pragma unroll
  for (int off = 32; off > 0; off >>= 1) {
    pnum += __shfl_down(pnum, off);
    pn1  += __shfl_down(pn1, off);
    pn2  += __shfl_down(pn2, off);
  }
  if ((t & 63) == 0) { redbuf[0][w] = pnum; redbuf[1][w] = pn1; redbuf[2][w] = pn2; }
  __syncthreads();
  if (t == 0) {
    float num = redbuf[0][0] + redbuf[0][1] + redbuf[0][2] + redbuf[0][3];
    float n1s = redbuf[1][0] + redbuf[1][1] + redbuf[1][2] + redbuf[1][3];
    float n2s = redbuf[2][0] + redbuf[2][1] + redbuf[2][2] + redbuf[2][3];
    float n1 = sqrtf(fmaxf(n1s, 0.f));
    float n2 = sqrtf(fmaxf(n2s, 0.f));
    out[pair] = num / ((n1 + 1e-8f) * (n2 + 1e-8f));
  }
}

extern "C" void kernel_launch(void* const* d_in, const int* in_sizes, int n_in,
                              void* d_out, int out_size, void* d_ws, size_t ws_size,
                              hipStream_t stream) {
  const float* v1    = (const float*)d_in[0];
  const float* v2    = (const float*)d_in[1];
  const float* w_img = (const float*)d_in[2];
  const float* w_txt = (const float*)d_in[3];
  const float* w1a   = (const float*)d_in[4];
  const float* b1a   = (const float*)d_in[5];
  const float* w2a   = (const float*)d_in[6];
  const float* b2a   = (const float*)d_in[7];
  const float* w1b   = (const float*)d_in[8];
  const float* b1b   = (const float*)d_in[9];
  const float* w2b   = (const float*)d_in[10];
  const float* b2b   = (const float*)d_in[11];
  float* out = (float*)d_out;

  // fp32 region
  float* ws   = (float*)d_ws;
  float* k1   = ws;                           // 1728*1024
  float* k2   = k1 + (size_t)1728 * 1024;     // 1440*1024
  float* G2a  = k2 + (size_t)1440 * 1024;     // 1440*1024
  float* G1b  = G2a + (size_t)1440 * 1024;    // 1728*1024
  float* Sbuf = G1b + (size_t)1728 * 1024;    // 1440*1728
  float* Cbuf = Sbuf + (size_t)1440 * 1728;   // 1440*1728
  float* g22  = Cbuf + (size_t)1440 * 1728;   // 48*900
  float* g11  = g22 + (size_t)48 * 900;       // 48*1296

  // split-bf16 fragment region
  unsigned short* fb    = (unsigned short*)(g11 + (size_t)48 * 1296);
  unsigned short* v1f   = fb;                                  // 108 tiles
  unsigned short* v2f   = v1f + (size_t)108 * 32768;           //  92 tiles
  unsigned short* k1f   = v2f + (size_t)92 * 32768;            // 108 tiles
  unsigned short* k2f   = k1f + (size_t)108 * 32768;           //  92 tiles
  unsigned short* wimgf = k2f + (size_t)92 * 32768;            //  64 tiles each
  unsigned short* wtxtf = wimgf + (size_t)64 * 32768;
  unsigned short* w1af  = wtxtf + (size_t)64 * 32768;
  unsigned short* w1bf  = w1af + (size_t)64 * 32768;
  unsigned short* G2aF  = w1bf + (size_t)64 * 32768;           // 48 * 65536 ush
  unsigned short* G1bF  = G2aF + (size_t)48 * 65536;           // 48 * 131072 ush

  // gram partial buffer ALIASES k1f (4 MB <= 6.9 MB): gram_reduce completes
  // before conv_k writes k1f (stream-ordered), so no conflict.
  float* pg = (float*)k1f;

  conv6<<<dim3(864, 6), 256, 0, stream>>>(v1, v2, w_img, w_txt, w1a, w1b,
                                          v1f, v2f, wimgf, wtxtf, w1af, w1bf);
  gram_partial<<<dim3(8, 96), 256, 0, stream>>>(v1, v2, pg);
  gram_reduce<<<96, 256, 0, stream>>>(pg, g11, g22);

  proj_fused<<<dim3(8, 14, 4), 256, 0, stream>>>(
      (const bf16x8*)v1f, (const bf16x8*)v2f, (const bf16x8*)wimgf,
      (const bf16x8*)wtxtf, (const bf16x8*)w1af, (const bf16x8*)w1bf,
      k1, k2, G2a, G1b);

  conv_k<<<dim3(864, 2), 256, 0, stream>>>(k1, k2, k1f, k2f);
  convG<<<dim3(768, 2), 256, 0, stream>>>(G2a, G1b, G2aF, G1bF);

  cross_fused<<<dim3(14, 12, 2), 256, 0, stream>>>(
      (const bf16x8*)k2f, (const bf16x8*)k1f, (const bf16x8*)v2f, (const bf16x8*)v1f,
      Sbuf, Cbuf);

  pair_kernel<<<2304, 256, 0, stream>>>(Sbuf, Cbuf, (const bf16x8*)G2aF, (const bf16x8*)G1bF,
                                        g22, g11, b1a, w2a, b2a, b1b, w2b, b2b, out);
}